// Round 1
// baseline (317.741 us; speedup 1.0000x reference)
//
#include <hip/hip_runtime.h>
#include <math.h>

#define B 8
#define N 1024
#define F 256
#define H 8
#define D 64
#define HD 512  // H*D

// ---------------------------------------------------------------------------
// K1: inv_norm[b*N+n] = rsqrt(max(sum(h^2), 1e-12))  — one wave per row
// ---------------------------------------------------------------------------
__global__ void k_norm(const float* __restrict__ h, float* __restrict__ invn) {
    int wave = (blockIdx.x * blockDim.x + threadIdx.x) >> 6;
    int lane = threadIdx.x & 63;
    if (wave >= B * N) return;
    float4 v = *reinterpret_cast<const float4*>(h + (size_t)wave * F + lane * 4);
    float s = v.x * v.x + v.y * v.y + v.z * v.z + v.w * v.w;
    #pragma unroll
    for (int off = 32; off; off >>= 1) s += __shfl_xor(s, off, 64);
    if (lane == 0) invn[wave] = rsqrtf(fmaxf(s, 1e-12f));
}

// ---------------------------------------------------------------------------
// K2: ht[b][hh][n][d] = sum_f h[b,n,f] * W[f, hh*D+d]
// block: 32 rows x 64 cols (one head). grid: (B*N/32, H)
// ---------------------------------------------------------------------------
__global__ __launch_bounds__(256) void k_proj(const float* __restrict__ h,
                                              const float* __restrict__ W,
                                              float* __restrict__ ht) {
    __shared__ float As[32][33];
    __shared__ float Bs[32][64];
    const int row0 = blockIdx.x * 32;
    const int hh = blockIdx.y;
    const int t = threadIdx.x;
    const int d = t & 63;   // lane -> output col
    const int w = t >> 6;   // wave id 0..3 -> row group
    float acc[8] = {0.f, 0.f, 0.f, 0.f, 0.f, 0.f, 0.f, 0.f};

    for (int f0 = 0; f0 < F; f0 += 32) {
        // stage A tile 32x32 (1024 floats, 1 float4/thread)
        {
            int r = t >> 3;
            int fq = (t & 7) * 4;
            float4 av = *reinterpret_cast<const float4*>(
                h + (size_t)(row0 + r) * F + f0 + fq);
            As[r][fq + 0] = av.x; As[r][fq + 1] = av.y;
            As[r][fq + 2] = av.z; As[r][fq + 3] = av.w;
        }
        // stage B tile 32x64 (2048 floats, 2 float4/thread)
        #pragma unroll
        for (int k = 0; k < 2; ++k) {
            int v = t + 256 * k;
            int f = v >> 4;
            int dq = (v & 15) * 4;
            float4 bv = *reinterpret_cast<const float4*>(
                W + (size_t)(f0 + f) * HD + hh * D + dq);
            Bs[f][dq + 0] = bv.x; Bs[f][dq + 1] = bv.y;
            Bs[f][dq + 2] = bv.z; Bs[f][dq + 3] = bv.w;
        }
        __syncthreads();
        #pragma unroll 8
        for (int f = 0; f < 32; ++f) {
            float bv = Bs[f][d];  // 64 lanes, 2 lanes/bank -> free
            #pragma unroll
            for (int rr = 0; rr < 8; ++rr)
                acc[rr] += As[rr * 4 + w][f] * bv;  // broadcast within wave
        }
        __syncthreads();
    }
    #pragma unroll
    for (int rr = 0; rr < 8; ++rr) {
        int row = row0 + rr * 4 + w;
        int b = row >> 10, n = row & 1023;
        ht[((size_t)((b * H + hh) * N + n)) * D + d] = acc[rr];  // coalesced
    }
}

// ---------------------------------------------------------------------------
// K3: src/tgt[b,h,n] = dot(ht[b,h,n,:], a[h, :D]) / a[h, D:] — one wave/row
// ---------------------------------------------------------------------------
__global__ void k_srctgt(const float* __restrict__ ht, const float* __restrict__ a,
                         float* __restrict__ src, float* __restrict__ tgt) {
    int wave = (blockIdx.x * blockDim.x + threadIdx.x) >> 6;
    int lane = threadIdx.x & 63;
    if (wave >= B * H * N) return;
    int hh = (wave >> 10) & 7;
    float v = ht[(size_t)wave * D + lane];
    float s = v * a[hh * 2 * D + lane];
    float tg = v * a[hh * 2 * D + D + lane];
    #pragma unroll
    for (int off = 32; off; off >>= 1) {
        s += __shfl_xor(s, off, 64);
        tg += __shfl_xor(tg, off, 64);
    }
    if (lane == 0) { src[wave] = s; tgt[wave] = tg; }
}

// ---------------------------------------------------------------------------
// K4: adjacency bitmask. block = (b, 32-row i-tile), loops over 32-row j-tiles.
// sim = (h_i*invn_i) . (h_j*invn_j); bit = sim > 0.5
// ---------------------------------------------------------------------------
__global__ __launch_bounds__(256) void k_adj(const float* __restrict__ h,
                                             const float* __restrict__ invn,
                                             unsigned* __restrict__ adj) {
    __shared__ float Hi[32][257];   // scalar reads, conflict-free (i+f)%32
    __shared__ float Hj[32][260];   // float4 reads (row stride 1040B, 16B-aligned), broadcast
    __shared__ unsigned adjw[32];
    const int b = blockIdx.x >> 5;
    const int i0 = (blockIdx.x & 31) * 32;
    const int t = threadIdx.x;

    // stage Hi (normalized): 8192 floats = 8 float4 per thread
    #pragma unroll
    for (int k = 0; k < 8; ++k) {
        int v = t + 256 * k;
        int r = v >> 6;
        int fq = (v & 63) * 4;
        float sc = invn[b * N + i0 + r];
        float4 av = *reinterpret_cast<const float4*>(
            h + ((size_t)(b * N + i0 + r)) * F + fq);
        Hi[r][fq + 0] = av.x * sc; Hi[r][fq + 1] = av.y * sc;
        Hi[r][fq + 2] = av.z * sc; Hi[r][fq + 3] = av.w * sc;
    }

    const int i = t & 31;
    const int jg = t >> 5;  // 0..7, each handles 4 j
    for (int jt = 0; jt < 32; ++jt) {
        __syncthreads();  // Hi ready (first iter) / prev iter done with Hj & adjw
        int j0 = jt * 32;
        #pragma unroll
        for (int k = 0; k < 8; ++k) {
            int v = t + 256 * k;
            int r = v >> 6;
            int fq = (v & 63) * 4;
            float sc = invn[b * N + j0 + r];
            float4 av = *reinterpret_cast<const float4*>(
                h + ((size_t)(b * N + j0 + r)) * F + fq);
            Hj[r][fq + 0] = av.x * sc; Hj[r][fq + 1] = av.y * sc;
            Hj[r][fq + 2] = av.z * sc; Hj[r][fq + 3] = av.w * sc;
        }
        if (t < 32) adjw[t] = 0u;
        __syncthreads();

        float a0 = 0.f, a1 = 0.f, a2 = 0.f, a3 = 0.f;
        #pragma unroll 4
        for (int f = 0; f < F; f += 4) {
            float4 j0v = *reinterpret_cast<const float4*>(&Hj[jg * 4 + 0][f]);
            float4 j1v = *reinterpret_cast<const float4*>(&Hj[jg * 4 + 1][f]);
            float4 j2v = *reinterpret_cast<const float4*>(&Hj[jg * 4 + 2][f]);
            float4 j3v = *reinterpret_cast<const float4*>(&Hj[jg * 4 + 3][f]);
            float h0 = Hi[i][f + 0], h1 = Hi[i][f + 1];
            float h2 = Hi[i][f + 2], h3 = Hi[i][f + 3];
            a0 += h0 * j0v.x + h1 * j0v.y + h2 * j0v.z + h3 * j0v.w;
            a1 += h0 * j1v.x + h1 * j1v.y + h2 * j1v.z + h3 * j1v.w;
            a2 += h0 * j2v.x + h1 * j2v.y + h2 * j2v.z + h3 * j2v.w;
            a3 += h0 * j3v.x + h1 * j3v.y + h2 * j3v.z + h3 * j3v.w;
        }
        unsigned m = 0;
        if (a0 > 0.5f) m |= 1u << (jg * 4 + 0);
        if (a1 > 0.5f) m |= 1u << (jg * 4 + 1);
        if (a2 > 0.5f) m |= 1u << (jg * 4 + 2);
        if (a3 > 0.5f) m |= 1u << (jg * 4 + 3);
        if (m) atomicOr(&adjw[i], m);
        __syncthreads();
        if (t < 32) adj[((size_t)(b * N + i0 + t)) * 32 + jt] = adjw[t];
    }
}

// ---------------------------------------------------------------------------
// K5: masked softmax + PV, sparse over adjacency set bits. One wave per
// (b,hh,i); lane = d. Online softmax; skipped entries == exp(-1e9-m) == 0.
// ---------------------------------------------------------------------------
__global__ void k_attn(const float* __restrict__ ht, const float* __restrict__ src,
                       const float* __restrict__ tgt, const unsigned* __restrict__ adj,
                       float* __restrict__ out) {
    int wave = (blockIdx.x * blockDim.x + threadIdx.x) >> 6;
    int lane = threadIdx.x & 63;
    if (wave >= B * H * N) return;
    int i = wave & 1023;
    int bh = wave >> 10;  // b*H + hh
    int b = bh >> 3;
    float s_i = src[wave];
    const unsigned* arow = adj + ((size_t)(b * N + i)) * 32;
    const float* htb = ht + (size_t)bh * N * D;
    const float* tgtb = tgt + (size_t)bh * N;
    float m = -INFINITY, l = 0.f, acc = 0.f;
    for (int wt = 0; wt < 32; ++wt) {
        unsigned word = arow[wt];
        while (word) {
            int jl = __builtin_ctz(word);
            word &= word - 1;
            int j = wt * 32 + jl;
            float e = s_i + tgtb[j];
            e = e > 0.f ? e : 0.2f * e;
            float mn = fmaxf(m, e);
            float sc = __expf(m - mn);   // exp(-inf)=0 on first hit
            float p  = __expf(e - mn);
            l = l * sc + p;
            acc = acc * sc + p * htb[(size_t)j * D + lane];
            m = mn;
        }
    }
    out[(size_t)wave * D + lane] = acc / l;  // diagonal always set -> l > 0
}

// ---------------------------------------------------------------------------
extern "C" void kernel_launch(void* const* d_in, const int* in_sizes, int n_in,
                              void* d_out, int out_size, void* d_ws, size_t ws_size,
                              hipStream_t stream) {
    const float* h = (const float*)d_in[0];   // [B,N,F]
    const float* W = (const float*)d_in[1];   // [F, H*D]
    const float* a = (const float*)d_in[2];   // [H, 2D, 1]
    float* out = (float*)d_out;               // [B,H,N,D] flat == [B,N,H*D] reshape

    char* ws = (char*)d_ws;
    // layout (bytes): invn 32768 | adj 1MB | src 256KB | tgt 256KB | ht 16MB  (~18.4MB)
    float*    invn = (float*)(ws + 0);
    unsigned* adj  = (unsigned*)(ws + 32768);
    float*    src  = (float*)(ws + 1081344);
    float*    tgt  = (float*)(ws + 1343488);
    float*    ht   = (float*)(ws + 1605632);

    k_norm<<<dim3((B * N) / 4), 256, 0, stream>>>(h, invn);
    k_proj<<<dim3((B * N) / 32, H), 256, 0, stream>>>(h, W, ht);
    k_srctgt<<<dim3((B * H * N) / 4), 256, 0, stream>>>(ht, a, src, tgt);
    k_adj<<<dim3(B * (N / 32)), 256, 0, stream>>>(h, invn, adj);
    k_attn<<<dim3((B * H * N) / 4), 256, 0, stream>>>(ht, src, tgt, adj, out);
}

// Round 2
// 113.425 us; speedup vs baseline: 2.8013x; 2.8013x over previous
//
#include <hip/hip_runtime.h>
#include <hip/hip_bf16.h>
#include <math.h>

#define B 8
#define N 1024
#define F 256
#define H 8
#define D 64
#define HD 512  // H*D

typedef __attribute__((ext_vector_type(8))) short bf16x8;
typedef __attribute__((ext_vector_type(16))) float f32x16;

__device__ __forceinline__ ushort f2bf(float x) {
    __hip_bfloat16 b = __float2bfloat16(x);
    return *reinterpret_cast<ushort*>(&b);
}

// ---------------------------------------------------------------------------
// K1: per-row L2 norm; writes normalized bf16 rows (hn) and raw bf16 rows (hb)
// one wave per row, lane = 4 floats
// ---------------------------------------------------------------------------
__global__ void k_norm(const float* __restrict__ h, ushort* __restrict__ hn,
                       ushort* __restrict__ hb) {
    int row = (blockIdx.x * blockDim.x + threadIdx.x) >> 6;
    int lane = threadIdx.x & 63;
    if (row >= B * N) return;
    float4 v = *reinterpret_cast<const float4*>(h + (size_t)row * F + lane * 4);
    float s = v.x * v.x + v.y * v.y + v.z * v.z + v.w * v.w;
    #pragma unroll
    for (int off = 32; off; off >>= 1) s += __shfl_xor(s, off, 64);
    float inv = rsqrtf(fmaxf(s, 1e-12f));
    ushort4 on, ob;
    on.x = f2bf(v.x * inv); on.y = f2bf(v.y * inv);
    on.z = f2bf(v.z * inv); on.w = f2bf(v.w * inv);
    ob.x = f2bf(v.x); ob.y = f2bf(v.y); ob.z = f2bf(v.z); ob.w = f2bf(v.w);
    *reinterpret_cast<ushort4*>(hn + (size_t)row * F + lane * 4) = on;
    *reinterpret_cast<ushort4*>(hb + (size_t)row * F + lane * 4) = ob;
}

// ---------------------------------------------------------------------------
// K1b: Wt[n][k] = bf16(W[k][n])  (transpose + convert, 256x512)
// ---------------------------------------------------------------------------
__global__ void k_wt(const float* __restrict__ W, ushort* __restrict__ Wt) {
    int idx = blockIdx.x * 256 + threadIdx.x;  // coalesced read over n
    int k = idx >> 9;
    int n = idx & 511;
    Wt[(size_t)n * F + k] = f2bf(W[idx]);
}

// ---------------------------------------------------------------------------
// K2: ht = h @ W via bf16 MFMA. block 128(M)x128(N), 4 waves 2x2, wave 64x64.
// A = hb [8192][256] bf16, B = Wt [512][256] bf16 (both row-major over k).
// LDS swizzle: byte ^= (row&7)<<4 (guide G4).
// ---------------------------------------------------------------------------
__global__ __launch_bounds__(256) void k_proj_mfma(const ushort* __restrict__ hb,
                                                   const ushort* __restrict__ Wt,
                                                   float* __restrict__ ht) {
    __shared__ ushort As[128 * 64];  // [r][k] 16KB
    __shared__ ushort Bs[128 * 64];  // [c][k] 16KB
    const int m0 = blockIdx.x * 128;
    const int n0 = blockIdx.y * 128;
    const int t = threadIdx.x;
    const int lane = t & 63;
    const int w = t >> 6;
    const int wr = w >> 1, wc = w & 1;

    f32x16 acc[2][2] = {};

    for (int f0 = 0; f0 < F; f0 += 64) {
        __syncthreads();
        #pragma unroll
        for (int c = t; c < 128 * 8; c += 256) {  // A: 1024 16B-chunks
            int r = c >> 3, cc = c & 7;
            uint4 v = *reinterpret_cast<const uint4*>(hb + (size_t)(m0 + r) * F + f0 + cc * 8);
            *reinterpret_cast<uint4*>((char*)As + r * 128 + ((cc * 16) ^ ((r & 7) << 4))) = v;
        }
        #pragma unroll
        for (int c = t; c < 128 * 8; c += 256) {  // B: 1024 16B-chunks
            int r = c >> 3, cc = c & 7;
            uint4 v = *reinterpret_cast<const uint4*>(Wt + (size_t)(n0 + r) * F + f0 + cc * 8);
            *reinterpret_cast<uint4*>((char*)Bs + r * 128 + ((cc * 16) ^ ((r & 7) << 4))) = v;
        }
        __syncthreads();
        #pragma unroll
        for (int kc = 0; kc < 4; ++kc) {
            int kb = kc * 32 + (lane >> 5) * 16;  // byte offset of this lane's 8 k's
            bf16x8 af[2], bf[2];
            #pragma unroll
            for (int tr = 0; tr < 2; ++tr) {
                int r = wr * 64 + tr * 32 + (lane & 31);
                af[tr] = *reinterpret_cast<const bf16x8*>((char*)As + r * 128 + (kb ^ ((r & 7) << 4)));
            }
            #pragma unroll
            for (int tc = 0; tc < 2; ++tc) {
                int r = wc * 64 + tc * 32 + (lane & 31);
                bf[tc] = *reinterpret_cast<const bf16x8*>((char*)Bs + r * 128 + (kb ^ ((r & 7) << 4)));
            }
            #pragma unroll
            for (int tr = 0; tr < 2; ++tr)
                #pragma unroll
                for (int tc = 0; tc < 2; ++tc)
                    acc[tr][tc] = __builtin_amdgcn_mfma_f32_32x32x16_bf16(af[tr], bf[tc], acc[tr][tc], 0, 0, 0);
        }
    }
    // epilogue: C[m][c] -> ht[b][head][n][d]; C layout col=lane&31, row=crow
    #pragma unroll
    for (int tr = 0; tr < 2; ++tr) {
        #pragma unroll
        for (int tc = 0; tc < 2; ++tc) {
            int col = n0 + wc * 64 + tc * 32 + (lane & 31);
            int head = col >> 6, d = col & 63;
            #pragma unroll
            for (int reg = 0; reg < 16; ++reg) {
                int m = m0 + wr * 64 + tr * 32 + (reg & 3) + 8 * (reg >> 2) + 4 * (lane >> 5);
                int b = m >> 10, n = m & 1023;
                ht[((size_t)((b * H + head) * N + n)) * D + d] = acc[tr][tc][reg];
            }
        }
    }
}

// ---------------------------------------------------------------------------
// K3: src/tgt[b,h,n] = dot(ht[b,h,n,:], a[h,:D] / a[h,D:]) — one wave/row
// ---------------------------------------------------------------------------
__global__ void k_srctgt(const float* __restrict__ ht, const float* __restrict__ a,
                         float* __restrict__ src, float* __restrict__ tgt) {
    int wave = (blockIdx.x * blockDim.x + threadIdx.x) >> 6;
    int lane = threadIdx.x & 63;
    if (wave >= B * H * N) return;
    int hh = (wave >> 10) & 7;
    float v = ht[(size_t)wave * D + lane];
    float s = v * a[hh * 2 * D + lane];
    float tg = v * a[hh * 2 * D + D + lane];
    #pragma unroll
    for (int off = 32; off; off >>= 1) {
        s += __shfl_xor(s, off, 64);
        tg += __shfl_xor(tg, off, 64);
    }
    if (lane == 0) { src[wave] = s; tgt[wave] = tg; }
}

// ---------------------------------------------------------------------------
// K4: adjacency bits via bf16 MFMA. block tile 128(i)x256(j), 4 waves 2x2,
// wave tile 64x128. grid (N/128, N/256, B). adj bit j of word (b,i,j>>5).
// ---------------------------------------------------------------------------
__global__ __launch_bounds__(256) void k_adj_mfma(const ushort* __restrict__ hn,
                                                  unsigned* __restrict__ adj) {
    __shared__ ushort As[128 * 64];  // i-rows   16KB
    __shared__ ushort Bs[256 * 64];  // j-rows   32KB
    const int b = blockIdx.z;
    const int i0 = blockIdx.x * 128;
    const int j0 = blockIdx.y * 256;
    const int t = threadIdx.x;
    const int lane = t & 63;
    const int w = t >> 6;
    const int wr = w >> 1, wc = w & 1;
    const ushort* hbase = hn + (size_t)b * N * F;

    f32x16 acc[2][4] = {};

    for (int f0 = 0; f0 < F; f0 += 64) {
        __syncthreads();
        #pragma unroll
        for (int c = t; c < 128 * 8; c += 256) {
            int r = c >> 3, cc = c & 7;
            uint4 v = *reinterpret_cast<const uint4*>(hbase + (size_t)(i0 + r) * F + f0 + cc * 8);
            *reinterpret_cast<uint4*>((char*)As + r * 128 + ((cc * 16) ^ ((r & 7) << 4))) = v;
        }
        #pragma unroll
        for (int c = t; c < 256 * 8; c += 256) {
            int r = c >> 3, cc = c & 7;
            uint4 v = *reinterpret_cast<const uint4*>(hbase + (size_t)(j0 + r) * F + f0 + cc * 8);
            *reinterpret_cast<uint4*>((char*)Bs + r * 128 + ((cc * 16) ^ ((r & 7) << 4))) = v;
        }
        __syncthreads();
        #pragma unroll
        for (int kc = 0; kc < 4; ++kc) {
            int kb = kc * 32 + (lane >> 5) * 16;
            bf16x8 af[2], bf[4];
            #pragma unroll
            for (int tr = 0; tr < 2; ++tr) {
                int r = wr * 64 + tr * 32 + (lane & 31);
                af[tr] = *reinterpret_cast<const bf16x8*>((char*)As + r * 128 + (kb ^ ((r & 7) << 4)));
            }
            #pragma unroll
            for (int tc = 0; tc < 4; ++tc) {
                int r = wc * 128 + tc * 32 + (lane & 31);
                bf[tc] = *reinterpret_cast<const bf16x8*>((char*)Bs + r * 128 + (kb ^ ((r & 7) << 4)));
            }
            #pragma unroll
            for (int tr = 0; tr < 2; ++tr)
                #pragma unroll
                for (int tc = 0; tc < 4; ++tc)
                    acc[tr][tc] = __builtin_amdgcn_mfma_f32_32x32x16_bf16(af[tr], bf[tc], acc[tr][tc], 0, 0, 0);
        }
    }
    // bits: ballot over 64 lanes gives rows (rbase, rbase+4) x 32 cols
    #pragma unroll
    for (int tr = 0; tr < 2; ++tr) {
        #pragma unroll
        for (int tc = 0; tc < 4; ++tc) {
            int wordcol = (j0 + wc * 128 + tc * 32) >> 5;
            #pragma unroll
            for (int reg = 0; reg < 16; ++reg) {
                unsigned long long msk = __ballot(acc[tr][tc][reg] > 0.5f);
                int rbase = i0 + wr * 64 + tr * 32 + (reg & 3) + 8 * (reg >> 2);
                if (lane == 0)
                    adj[(size_t)(b * N + rbase) * 32 + wordcol] = (unsigned)msk;
                if (lane == 32)
                    adj[(size_t)(b * N + rbase + 4) * 32 + wordcol] = (unsigned)(msk >> 32);
            }
        }
    }
}

// ---------------------------------------------------------------------------
// K5: masked softmax + PV, sparse over adjacency set bits. One wave per
// (b,hh,i); lane = d. Online softmax; skipped entries == exp(-1e9-m) == 0.
// ---------------------------------------------------------------------------
__global__ void k_attn(const float* __restrict__ ht, const float* __restrict__ src,
                       const float* __restrict__ tgt, const unsigned* __restrict__ adj,
                       float* __restrict__ out) {
    int wave = (blockIdx.x * blockDim.x + threadIdx.x) >> 6;
    int lane = threadIdx.x & 63;
    if (wave >= B * H * N) return;
    int i = wave & 1023;
    int bh = wave >> 10;  // b*H + hh
    int b = bh >> 3;
    float s_i = src[wave];
    const unsigned* arow = adj + ((size_t)(b * N + i)) * 32;
    const float* htb = ht + (size_t)bh * N * D;
    const float* tgtb = tgt + (size_t)bh * N;
    float m = -INFINITY, l = 0.f, acc = 0.f;
    for (int wt = 0; wt < 32; ++wt) {
        unsigned word = arow[wt];
        while (word) {
            int jl = __builtin_ctz(word);
            word &= word - 1;
            int j = wt * 32 + jl;
            float e = s_i + tgtb[j];
            e = e > 0.f ? e : 0.2f * e;
            float mn = fmaxf(m, e);
            float sc = __expf(m - mn);   // exp(-inf)=0 on first hit
            float p  = __expf(e - mn);
            l = l * sc + p;
            acc = acc * sc + p * htb[(size_t)j * D + lane];
            m = mn;
        }
    }
    out[(size_t)wave * D + lane] = acc / l;  // diagonal always set -> l > 0
}

// ---------------------------------------------------------------------------
extern "C" void kernel_launch(void* const* d_in, const int* in_sizes, int n_in,
                              void* d_out, int out_size, void* d_ws, size_t ws_size,
                              hipStream_t stream) {
    const float* h = (const float*)d_in[0];   // [B,N,F]
    const float* W = (const float*)d_in[1];   // [F, H*D]
    const float* a = (const float*)d_in[2];   // [H, 2D, 1]
    float* out = (float*)d_out;               // [B,H,N,D] flat == [B,N,H*D] reshape

    char* ws = (char*)d_ws;
    // layout (bytes):
    unsigned* adj = (unsigned*)(ws + 0);          // 1 MB
    float*    src = (float*)(ws + 1048576);       // 256 KB
    float*    tgt = (float*)(ws + 1310720);       // 256 KB
    float*    ht  = (float*)(ws + 1572864);       // 16 MB
    ushort*   hn  = (ushort*)(ws + 18350080);     // 4 MB  normalized bf16
    ushort*   hb  = (ushort*)(ws + 22544384);     // 4 MB  raw bf16
    ushort*   Wt  = (ushort*)(ws + 26738688);     // 256 KB transposed bf16
    // total ~25.75 MB

    k_norm<<<dim3((B * N) / 4), 256, 0, stream>>>(h, hn, hb);
    k_wt<<<dim3((F * HD) / 256), 256, 0, stream>>>(W, Wt);
    k_proj_mfma<<<dim3((B * N) / 128, HD / 128), 256, 0, stream>>>(hb, Wt, ht);
    k_srctgt<<<dim3((B * H * N) / 4), 256, 0, stream>>>(ht, a, src, tgt);
    k_adj_mfma<<<dim3(N / 128, N / 256, B), 256, 0, stream>>>(hn, adj);
    k_attn<<<dim3((B * H * N) / 4), 256, 0, stream>>>(ht, src, tgt, adj, out);
}

// Round 3
// 74.706 us; speedup vs baseline: 4.2532x; 1.5183x over previous
//
#include <hip/hip_runtime.h>
#include <hip/hip_bf16.h>
#include <math.h>

#define B 8
#define N 1024
#define F 256
#define H 8
#define D 64
#define HD 512  // H*D

typedef __attribute__((ext_vector_type(8))) short bf16x8;
typedef __attribute__((ext_vector_type(16))) float f32x16;

__device__ __forceinline__ ushort f2bf(float x) {
    __hip_bfloat16 b = __float2bfloat16(x);
    return *reinterpret_cast<ushort*>(&b);
}

// ---------------------------------------------------------------------------
// K1: per-row L2 norm; writes normalized bf16 rows (hn) and raw bf16 rows (hb)
// ---------------------------------------------------------------------------
__global__ void k_norm(const float* __restrict__ h, ushort* __restrict__ hn,
                       ushort* __restrict__ hb) {
    int row = (blockIdx.x * blockDim.x + threadIdx.x) >> 6;
    int lane = threadIdx.x & 63;
    if (row >= B * N) return;
    float4 v = *reinterpret_cast<const float4*>(h + (size_t)row * F + lane * 4);
    float s = v.x * v.x + v.y * v.y + v.z * v.z + v.w * v.w;
    #pragma unroll
    for (int off = 32; off; off >>= 1) s += __shfl_xor(s, off, 64);
    float inv = rsqrtf(fmaxf(s, 1e-12f));
    ushort4 on, ob;
    on.x = f2bf(v.x * inv); on.y = f2bf(v.y * inv);
    on.z = f2bf(v.z * inv); on.w = f2bf(v.w * inv);
    ob.x = f2bf(v.x); ob.y = f2bf(v.y); ob.z = f2bf(v.z); ob.w = f2bf(v.w);
    *reinterpret_cast<ushort4*>(hn + (size_t)row * F + lane * 4) = on;
    *reinterpret_cast<ushort4*>(hb + (size_t)row * F + lane * 4) = ob;
}

// ---------------------------------------------------------------------------
// K1b: Wt[n][k] = bf16(W[k][n])
// ---------------------------------------------------------------------------
__global__ void k_wt(const float* __restrict__ W, ushort* __restrict__ Wt) {
    int idx = blockIdx.x * 256 + threadIdx.x;  // coalesced read over n
    int k = idx >> 9;
    int n = idx & 511;
    Wt[(size_t)n * F + k] = f2bf(W[idx]);
}

// ---------------------------------------------------------------------------
// K2: ht = h @ W via bf16 MFMA, fused src/tgt epilogue.
// block 128(M)x128(N), 4 waves 2x2, wave 64x64 (= one head's full D).
// ---------------------------------------------------------------------------
__global__ __launch_bounds__(256) void k_proj_mfma(const ushort* __restrict__ hb,
                                                   const ushort* __restrict__ Wt,
                                                   const float* __restrict__ a,
                                                   float* __restrict__ ht,
                                                   float* __restrict__ src,
                                                   float* __restrict__ tgt) {
    __shared__ ushort As[128 * 64];  // 16KB
    __shared__ ushort Bs[128 * 64];  // 16KB
    const int m0 = blockIdx.x * 128;
    const int n0 = blockIdx.y * 128;
    const int t = threadIdx.x;
    const int lane = t & 63;
    const int w = t >> 6;
    const int wr = w >> 1, wc = w & 1;

    f32x16 acc[2][2] = {};

    for (int f0 = 0; f0 < F; f0 += 64) {
        __syncthreads();
        #pragma unroll
        for (int c = t; c < 128 * 8; c += 256) {
            int r = c >> 3, cc = c & 7;
            uint4 v = *reinterpret_cast<const uint4*>(hb + (size_t)(m0 + r) * F + f0 + cc * 8);
            *reinterpret_cast<uint4*>((char*)As + r * 128 + ((cc * 16) ^ ((r & 7) << 4))) = v;
        }
        #pragma unroll
        for (int c = t; c < 128 * 8; c += 256) {
            int r = c >> 3, cc = c & 7;
            uint4 v = *reinterpret_cast<const uint4*>(Wt + (size_t)(n0 + r) * F + f0 + cc * 8);
            *reinterpret_cast<uint4*>((char*)Bs + r * 128 + ((cc * 16) ^ ((r & 7) << 4))) = v;
        }
        __syncthreads();
        #pragma unroll
        for (int kc = 0; kc < 4; ++kc) {
            int kb = kc * 32 + (lane >> 5) * 16;
            bf16x8 af[2], bf[2];
            #pragma unroll
            for (int tr = 0; tr < 2; ++tr) {
                int r = wr * 64 + tr * 32 + (lane & 31);
                af[tr] = *reinterpret_cast<const bf16x8*>((char*)As + r * 128 + (kb ^ ((r & 7) << 4)));
            }
            #pragma unroll
            for (int tc = 0; tc < 2; ++tc) {
                int r = wc * 64 + tc * 32 + (lane & 31);
                bf[tc] = *reinterpret_cast<const bf16x8*>((char*)Bs + r * 128 + (kb ^ ((r & 7) << 4)));
            }
            #pragma unroll
            for (int tr = 0; tr < 2; ++tr)
                #pragma unroll
                for (int tc = 0; tc < 2; ++tc)
                    acc[tr][tc] = __builtin_amdgcn_mfma_f32_32x32x16_bf16(af[tr], bf[tc], acc[tr][tc], 0, 0, 0);
        }
    }
    // ht store: C layout col=lane&31, row=(reg&3)+8*(reg>>2)+4*(lane>>5)
    const int head = (n0 >> 6) + wc;  // wave's 64 cols = one full head
    #pragma unroll
    for (int tr = 0; tr < 2; ++tr) {
        #pragma unroll
        for (int tc = 0; tc < 2; ++tc) {
            int d = tc * 32 + (lane & 31);
            #pragma unroll
            for (int reg = 0; reg < 16; ++reg) {
                int m = m0 + wr * 64 + tr * 32 + (reg & 3) + 8 * (reg >> 2) + 4 * (lane >> 5);
                int b = m >> 10, n = m & 1023;
                ht[((size_t)((b * H + head) * N + n)) * D + d] = acc[tr][tc][reg];
            }
        }
    }
    // fused src/tgt: dot each owned row with a[head,:D] / a[head,D:]
    const int dl = lane & 31;
    float as0 = a[head * 2 * D + dl];
    float as1 = a[head * 2 * D + 32 + dl];
    float at0 = a[head * 2 * D + D + dl];
    float at1 = a[head * 2 * D + D + 32 + dl];
    #pragma unroll
    for (int tr = 0; tr < 2; ++tr) {
        #pragma unroll
        for (int reg = 0; reg < 16; ++reg) {
            float s  = acc[tr][0][reg] * as0 + acc[tr][1][reg] * as1;
            float tg = acc[tr][0][reg] * at0 + acc[tr][1][reg] * at1;
            #pragma unroll
            for (int off = 16; off; off >>= 1) {
                s  += __shfl_xor(s, off, 64);
                tg += __shfl_xor(tg, off, 64);
            }
            if (dl == 0) {
                int m = m0 + wr * 64 + tr * 32 + (reg & 3) + 8 * (reg >> 2) + 4 * (lane >> 5);
                int b = m >> 10, n = m & 1023;
                size_t idx = (size_t)(b * H + head) * N + n;
                src[idx] = s;
                tgt[idx] = tg;
            }
        }
    }
}

// ---------------------------------------------------------------------------
// K4: adjacency bits via bf16 MFMA. block 128(i)x256(j), 4 waves 2x2.
// ---------------------------------------------------------------------------
__global__ __launch_bounds__(256) void k_adj_mfma(const ushort* __restrict__ hn,
                                                  unsigned* __restrict__ adj) {
    __shared__ ushort As[128 * 64];  // 16KB
    __shared__ ushort Bs[256 * 64];  // 32KB
    const int b = blockIdx.z;
    const int i0 = blockIdx.x * 128;
    const int j0 = blockIdx.y * 256;
    const int t = threadIdx.x;
    const int lane = t & 63;
    const int w = t >> 6;
    const int wr = w >> 1, wc = w & 1;
    const ushort* hbase = hn + (size_t)b * N * F;

    f32x16 acc[2][4] = {};

    for (int f0 = 0; f0 < F; f0 += 64) {
        __syncthreads();
        #pragma unroll
        for (int c = t; c < 128 * 8; c += 256) {
            int r = c >> 3, cc = c & 7;
            uint4 v = *reinterpret_cast<const uint4*>(hbase + (size_t)(i0 + r) * F + f0 + cc * 8);
            *reinterpret_cast<uint4*>((char*)As + r * 128 + ((cc * 16) ^ ((r & 7) << 4))) = v;
        }
        #pragma unroll
        for (int c = t; c < 256 * 8; c += 256) {
            int r = c >> 3, cc = c & 7;
            uint4 v = *reinterpret_cast<const uint4*>(hbase + (size_t)(j0 + r) * F + f0 + cc * 8);
            *reinterpret_cast<uint4*>((char*)Bs + r * 128 + ((cc * 16) ^ ((r & 7) << 4))) = v;
        }
        __syncthreads();
        #pragma unroll
        for (int kc = 0; kc < 4; ++kc) {
            int kb = kc * 32 + (lane >> 5) * 16;
            bf16x8 af[2], bf[4];
            #pragma unroll
            for (int tr = 0; tr < 2; ++tr) {
                int r = wr * 64 + tr * 32 + (lane & 31);
                af[tr] = *reinterpret_cast<const bf16x8*>((char*)As + r * 128 + (kb ^ ((r & 7) << 4)));
            }
            #pragma unroll
            for (int tc = 0; tc < 4; ++tc) {
                int r = wc * 128 + tc * 32 + (lane & 31);
                bf[tc] = *reinterpret_cast<const bf16x8*>((char*)Bs + r * 128 + (kb ^ ((r & 7) << 4)));
            }
            #pragma unroll
            for (int tr = 0; tr < 2; ++tr)
                #pragma unroll
                for (int tc = 0; tc < 4; ++tc)
                    acc[tr][tc] = __builtin_amdgcn_mfma_f32_32x32x16_bf16(af[tr], bf[tc], acc[tr][tc], 0, 0, 0);
        }
    }
    #pragma unroll
    for (int tr = 0; tr < 2; ++tr) {
        #pragma unroll
        for (int tc = 0; tc < 4; ++tc) {
            int wordcol = (j0 + wc * 128 + tc * 32) >> 5;
            #pragma unroll
            for (int reg = 0; reg < 16; ++reg) {
                unsigned long long msk = __ballot(acc[tr][tc][reg] > 0.5f);
                int rbase = i0 + wr * 64 + tr * 32 + (reg & 3) + 8 * (reg >> 2);
                if (lane == 0)
                    adj[(size_t)(b * N + rbase) * 32 + wordcol] = (unsigned)msk;
                if (lane == 32)
                    adj[(size_t)(b * N + rbase + 4) * 32 + wordcol] = (unsigned)(msk >> 32);
            }
        }
    }
}

// ---------------------------------------------------------------------------
// K5: sparse masked softmax + PV. One wave per (b,hh,i); lane = d.
// Vectorized adjacency scan: lanes 0-31 hold the full 32-word row; ballot
// finds non-zero words; iterate only those.
// ---------------------------------------------------------------------------
__global__ void k_attn(const float* __restrict__ ht, const float* __restrict__ src,
                       const float* __restrict__ tgt, const unsigned* __restrict__ adj,
                       float* __restrict__ out) {
    int wave = (blockIdx.x * blockDim.x + threadIdx.x) >> 6;
    int lane = threadIdx.x & 63;
    if (wave >= B * H * N) return;
    int i = wave & 1023;
    int bh = wave >> 10;  // b*H + hh
    int b = bh >> 3;
    float s_i = src[wave];
    const unsigned* arow = adj + ((size_t)(b * N + i)) * 32;
    const float* htb = ht + (size_t)bh * N * D;
    const float* tgtb = tgt + (size_t)bh * N;
    unsigned myword = (lane < 32) ? arow[lane] : 0u;
    unsigned long long nz = __ballot(myword != 0u);
    float m = -INFINITY, l = 0.f, acc = 0.f;
    while (nz) {
        int wt = __builtin_ctzll(nz);
        nz &= nz - 1;
        unsigned word = (unsigned)__shfl((int)myword, wt, 64);
        while (word) {
            int jl = __builtin_ctz(word);
            word &= word - 1;
            int j = wt * 32 + jl;
            float e = s_i + tgtb[j];
            e = e > 0.f ? e : 0.2f * e;
            float mn = fmaxf(m, e);
            float sc = __expf(m - mn);   // exp(-inf)=0 on first hit
            float p  = __expf(e - mn);
            l = l * sc + p;
            acc = acc * sc + p * htb[(size_t)j * D + lane];
            m = mn;
        }
    }
    out[(size_t)wave * D + lane] = acc / l;  // diagonal always set -> l > 0
}

// ---------------------------------------------------------------------------
extern "C" void kernel_launch(void* const* d_in, const int* in_sizes, int n_in,
                              void* d_out, int out_size, void* d_ws, size_t ws_size,
                              hipStream_t stream) {
    const float* h = (const float*)d_in[0];   // [B,N,F]
    const float* W = (const float*)d_in[1];   // [F, H*D]
    const float* a = (const float*)d_in[2];   // [H, 2D, 1]
    float* out = (float*)d_out;               // [B,H,N,D] flat == [B,N,H*D] reshape

    char* ws = (char*)d_ws;
    unsigned* adj = (unsigned*)(ws + 0);          // 1 MB
    float*    src = (float*)(ws + 1048576);       // 256 KB
    float*    tgt = (float*)(ws + 1310720);       // 256 KB
    float*    ht  = (float*)(ws + 1572864);       // 16 MB
    ushort*   hn  = (ushort*)(ws + 18350080);     // 4 MB
    ushort*   hb  = (ushort*)(ws + 22544384);     // 4 MB
    ushort*   Wt  = (ushort*)(ws + 26738688);     // 256 KB

    k_norm<<<dim3((B * N) / 4), 256, 0, stream>>>(h, hn, hb);
    k_wt<<<dim3((F * HD) / 256), 256, 0, stream>>>(W, Wt);
    k_proj_mfma<<<dim3((B * N) / 128, HD / 128), 256, 0, stream>>>(hb, Wt, a, ht, src, tgt);
    k_adj_mfma<<<dim3(N / 128, N / 256, B), 256, 0, stream>>>(hn, adj);
    k_attn<<<dim3((B * H * N) / 4), 256, 0, stream>>>(ht, src, tgt, adj, out);
}

// Round 4
// 52.389 us; speedup vs baseline: 6.0650x; 1.4260x over previous
//
#include <hip/hip_runtime.h>
#include <hip/hip_bf16.h>
#include <math.h>

#define B 8
#define N 1024
#define F 256
#define H 8
#define D 64
#define HD 512  // H*D

typedef __attribute__((ext_vector_type(8))) short bf16x8;
typedef __attribute__((ext_vector_type(16))) float f32x16;

__device__ __forceinline__ ushort f2bf(float x) {
    __hip_bfloat16 b = __float2bfloat16(x);
    return *reinterpret_cast<ushort*>(&b);
}

// ---------------------------------------------------------------------------
// K1: prep. blocks 0..2047: per-row L2 norm -> hn (normalized bf16) + hb (raw
// bf16), one wave per row. blocks 2048..2559: Wt[n][k] = bf16(W[k][n]).
// ---------------------------------------------------------------------------
__global__ __launch_bounds__(256) void k_prep(const float* __restrict__ h,
                                              const float* __restrict__ W,
                                              ushort* __restrict__ hn,
                                              ushort* __restrict__ hb,
                                              ushort* __restrict__ Wt) {
    if (blockIdx.x < 2048) {
        int row = (blockIdx.x * 256 + threadIdx.x) >> 6;
        int lane = threadIdx.x & 63;
        float4 v = *reinterpret_cast<const float4*>(h + (size_t)row * F + lane * 4);
        float s = v.x * v.x + v.y * v.y + v.z * v.z + v.w * v.w;
        #pragma unroll
        for (int off = 32; off; off >>= 1) s += __shfl_xor(s, off, 64);
        float inv = rsqrtf(fmaxf(s, 1e-12f));
        ushort4 on, ob;
        on.x = f2bf(v.x * inv); on.y = f2bf(v.y * inv);
        on.z = f2bf(v.z * inv); on.w = f2bf(v.w * inv);
        ob.x = f2bf(v.x); ob.y = f2bf(v.y); ob.z = f2bf(v.z); ob.w = f2bf(v.w);
        *reinterpret_cast<ushort4*>(hn + (size_t)row * F + lane * 4) = on;
        *reinterpret_cast<ushort4*>(hb + (size_t)row * F + lane * 4) = ob;
    } else {
        int idx = (blockIdx.x - 2048) * 256 + threadIdx.x;  // coalesced over n
        int k = idx >> 9;
        int n = idx & 511;
        Wt[(size_t)n * F + k] = f2bf(W[idx]);
    }
}

// ---------------------------------------------------------------------------
// K2: fused MFMA kernel.
// blocks [0,512):   proj  ht = hb @ Wt^T, tile 64(M)x128(N), + src/tgt epilogue
// blocks [512,1024): adj  bits of (hn·hn^T > 0.5), tile 128(i)x128(j)
// 4 waves each; LDS 32KB; 4 blocks/CU co-resident for latency hiding.
// ---------------------------------------------------------------------------
#define SWZ(r, byte) ((byte) ^ (((r) & 7) << 4))

__global__ __launch_bounds__(256) void k_gemm(const ushort* __restrict__ hb,
                                              const ushort* __restrict__ Wt,
                                              const ushort* __restrict__ hn,
                                              const float* __restrict__ a,
                                              float* __restrict__ ht,
                                              float* __restrict__ src,
                                              float* __restrict__ tgt,
                                              unsigned* __restrict__ adj) {
    __shared__ ushort As[128 * 64];  // 16KB
    __shared__ ushort Bs[128 * 64];  // 16KB
    const int bid = blockIdx.x;
    const int t = threadIdx.x;
    const int lane = t & 63;
    const int w = t >> 6;
    const int wr = w >> 1, wc = w & 1;

    if (bid < 512) {
        // ---------------- projection path ----------------
        const int m0 = (bid >> 2) * 64;
        const int n0 = (bid & 3) * 128;
        f32x16 acc[2] = {};

        for (int f0 = 0; f0 < F; f0 += 64) {
            __syncthreads();
            #pragma unroll
            for (int c = t; c < 64 * 8; c += 256) {
                int r = c >> 3, cc = c & 7;
                uint4 v = *reinterpret_cast<const uint4*>(hb + (size_t)(m0 + r) * F + f0 + cc * 8);
                *reinterpret_cast<uint4*>((char*)As + r * 128 + SWZ(r, cc * 16)) = v;
            }
            #pragma unroll
            for (int c = t; c < 128 * 8; c += 256) {
                int r = c >> 3, cc = c & 7;
                uint4 v = *reinterpret_cast<const uint4*>(Wt + (size_t)(n0 + r) * F + f0 + cc * 8);
                *reinterpret_cast<uint4*>((char*)Bs + r * 128 + SWZ(r, cc * 16)) = v;
            }
            __syncthreads();
            #pragma unroll
            for (int kc = 0; kc < 4; ++kc) {
                int kb = kc * 32 + (lane >> 5) * 16;
                int ra = wr * 32 + (lane & 31);
                bf16x8 af = *reinterpret_cast<const bf16x8*>((char*)As + ra * 128 + SWZ(ra, kb));
                #pragma unroll
                for (int tc = 0; tc < 2; ++tc) {
                    int rb = wc * 64 + tc * 32 + (lane & 31);
                    bf16x8 bf = *reinterpret_cast<const bf16x8*>((char*)Bs + rb * 128 + SWZ(rb, kb));
                    acc[tc] = __builtin_amdgcn_mfma_f32_32x32x16_bf16(af, bf, acc[tc], 0, 0, 0);
                }
            }
        }
        // ht store
        const int head = (n0 >> 6) + wc;
        #pragma unroll
        for (int tc = 0; tc < 2; ++tc) {
            int d = tc * 32 + (lane & 31);
            #pragma unroll
            for (int reg = 0; reg < 16; ++reg) {
                int m = m0 + wr * 32 + (reg & 3) + 8 * (reg >> 2) + 4 * (lane >> 5);
                int b = m >> 10, n = m & 1023;
                ht[((size_t)((b * H + head) * N + n)) * D + d] = acc[tc][reg];
            }
        }
        // fused src/tgt
        const int dl = lane & 31;
        float as0 = a[head * 2 * D + dl];
        float as1 = a[head * 2 * D + 32 + dl];
        float at0 = a[head * 2 * D + D + dl];
        float at1 = a[head * 2 * D + D + 32 + dl];
        #pragma unroll
        for (int reg = 0; reg < 16; ++reg) {
            float s  = acc[0][reg] * as0 + acc[1][reg] * as1;
            float tg = acc[0][reg] * at0 + acc[1][reg] * at1;
            #pragma unroll
            for (int off = 16; off; off >>= 1) {
                s  += __shfl_xor(s, off, 64);
                tg += __shfl_xor(tg, off, 64);
            }
            if (dl == 0) {
                int m = m0 + wr * 32 + (reg & 3) + 8 * (reg >> 2) + 4 * (lane >> 5);
                int b = m >> 10, n = m & 1023;
                size_t idx = (size_t)(b * H + head) * N + n;
                src[idx] = s;
                tgt[idx] = tg;
            }
        }
    } else {
        // ---------------- adjacency path ----------------
        const int bid2 = bid - 512;
        const int b = bid2 >> 6;
        const int i0 = ((bid2 >> 3) & 7) * 128;
        const int j0 = (bid2 & 7) * 128;
        const ushort* hbase = hn + (size_t)b * N * F;
        f32x16 acc[2][2] = {};

        for (int f0 = 0; f0 < F; f0 += 64) {
            __syncthreads();
            #pragma unroll
            for (int c = t; c < 128 * 8; c += 256) {
                int r = c >> 3, cc = c & 7;
                uint4 v = *reinterpret_cast<const uint4*>(hbase + (size_t)(i0 + r) * F + f0 + cc * 8);
                *reinterpret_cast<uint4*>((char*)As + r * 128 + SWZ(r, cc * 16)) = v;
            }
            #pragma unroll
            for (int c = t; c < 128 * 8; c += 256) {
                int r = c >> 3, cc = c & 7;
                uint4 v = *reinterpret_cast<const uint4*>(hbase + (size_t)(j0 + r) * F + f0 + cc * 8);
                *reinterpret_cast<uint4*>((char*)Bs + r * 128 + SWZ(r, cc * 16)) = v;
            }
            __syncthreads();
            #pragma unroll
            for (int kc = 0; kc < 4; ++kc) {
                int kb = kc * 32 + (lane >> 5) * 16;
                bf16x8 af[2], bf[2];
                #pragma unroll
                for (int tr = 0; tr < 2; ++tr) {
                    int r = wr * 64 + tr * 32 + (lane & 31);
                    af[tr] = *reinterpret_cast<const bf16x8*>((char*)As + r * 128 + SWZ(r, kb));
                }
                #pragma unroll
                for (int tc = 0; tc < 2; ++tc) {
                    int r = wc * 64 + tc * 32 + (lane & 31);
                    bf[tc] = *reinterpret_cast<const bf16x8*>((char*)Bs + r * 128 + SWZ(r, kb));
                }
                #pragma unroll
                for (int tr = 0; tr < 2; ++tr)
                    #pragma unroll
                    for (int tc = 0; tc < 2; ++tc)
                        acc[tr][tc] = __builtin_amdgcn_mfma_f32_32x32x16_bf16(af[tr], bf[tc], acc[tr][tc], 0, 0, 0);
            }
        }
        #pragma unroll
        for (int tr = 0; tr < 2; ++tr) {
            #pragma unroll
            for (int tc = 0; tc < 2; ++tc) {
                int wordcol = (j0 + wc * 64 + tc * 32) >> 5;
                #pragma unroll
                for (int reg = 0; reg < 16; ++reg) {
                    unsigned long long msk = __ballot(acc[tr][tc][reg] > 0.5f);
                    int rbase = i0 + wr * 64 + tr * 32 + (reg & 3) + 8 * (reg >> 2);
                    if (lane == 0)
                        adj[(size_t)(b * N + rbase) * 32 + wordcol] = (unsigned)msk;
                    if (lane == 32)
                        adj[(size_t)(b * N + rbase + 4) * 32 + wordcol] = (unsigned)(msk >> 32);
                }
            }
        }
    }
}

// ---------------------------------------------------------------------------
// K5: sparse masked softmax + PV. One wave per (b,hh,i); lane = d.
// Lanes 0-31 hold the 32-word adjacency row; ballot -> non-zero words.
// Fast path: single set bit -> softmax weight 1 -> copy ht row.
// ---------------------------------------------------------------------------
__global__ void k_attn(const float* __restrict__ ht, const float* __restrict__ src,
                       const float* __restrict__ tgt, const unsigned* __restrict__ adj,
                       float* __restrict__ out) {
    int wave = (blockIdx.x * blockDim.x + threadIdx.x) >> 6;
    int lane = threadIdx.x & 63;
    if (wave >= B * H * N) return;
    int i = wave & 1023;
    int bh = wave >> 10;  // b*H + hh
    int b = bh >> 3;
    const unsigned* arow = adj + ((size_t)(b * N + i)) * 32;
    const float* htb = ht + (size_t)bh * N * D;
    unsigned myword = (lane < 32) ? arow[lane] : 0u;
    unsigned long long nz = __ballot(myword != 0u);

    if ((nz & (nz - 1)) == 0ull) {
        // exactly one non-zero word
        int wt = __builtin_ctzll(nz);
        unsigned word = (unsigned)__shfl((int)myword, wt, 64);
        if ((word & (word - 1)) == 0u) {
            // exactly one set bit total: weight == 1, out = ht row
            int j = wt * 32 + __builtin_ctz(word);
            out[(size_t)wave * D + lane] = htb[(size_t)j * D + lane];
            return;
        }
    }

    float s_i = src[wave];
    const float* tgtb = tgt + (size_t)bh * N;
    float m = -INFINITY, l = 0.f, acc = 0.f;
    while (nz) {
        int wt = __builtin_ctzll(nz);
        nz &= nz - 1;
        unsigned word = (unsigned)__shfl((int)myword, wt, 64);
        while (word) {
            int jl = __builtin_ctz(word);
            word &= word - 1;
            int j = wt * 32 + jl;
            float e = s_i + tgtb[j];
            e = e > 0.f ? e : 0.2f * e;
            float mn = fmaxf(m, e);
            float sc = __expf(m - mn);   // exp(-inf)=0 on first hit
            float p  = __expf(e - mn);
            l = l * sc + p;
            acc = acc * sc + p * htb[(size_t)j * D + lane];
            m = mn;
        }
    }
    out[(size_t)wave * D + lane] = acc / l;
}

// ---------------------------------------------------------------------------
extern "C" void kernel_launch(void* const* d_in, const int* in_sizes, int n_in,
                              void* d_out, int out_size, void* d_ws, size_t ws_size,
                              hipStream_t stream) {
    const float* h = (const float*)d_in[0];   // [B,N,F]
    const float* W = (const float*)d_in[1];   // [F, H*D]
    const float* a = (const float*)d_in[2];   // [H, 2D, 1]
    float* out = (float*)d_out;               // [B,H,N,D] flat == [B,N,H*D] reshape

    char* ws = (char*)d_ws;
    unsigned* adj = (unsigned*)(ws + 0);          // 1 MB
    float*    src = (float*)(ws + 1048576);       // 256 KB
    float*    tgt = (float*)(ws + 1310720);       // 256 KB
    float*    ht  = (float*)(ws + 1572864);       // 16 MB
    ushort*   hn  = (ushort*)(ws + 18350080);     // 4 MB
    ushort*   hb  = (ushort*)(ws + 22544384);     // 4 MB
    ushort*   Wt  = (ushort*)(ws + 26738688);     // 256 KB

    k_prep<<<dim3(2560), 256, 0, stream>>>(h, W, hn, hb, Wt);
    k_gemm<<<dim3(1024), 256, 0, stream>>>(hb, Wt, hn, a, ht, src, tgt, adj);
    k_attn<<<dim3((B * H * N) / 4), 256, 0, stream>>>(ht, src, tgt, adj, out);
}

// Round 5
// 37.863 us; speedup vs baseline: 8.3918x; 1.3836x over previous
//
#include <hip/hip_runtime.h>
#include <hip/hip_bf16.h>
#include <math.h>

#define B 8
#define N 1024
#define F 256
#define H 8
#define D 64
#define HD 512  // H*D

typedef __attribute__((ext_vector_type(8))) short bf16x8;
typedef __attribute__((ext_vector_type(16))) float f32x16;

__device__ __forceinline__ ushort f2bf(float x) {
    __hip_bfloat16 b = __float2bfloat16(x);
    return *reinterpret_cast<ushort*>(&b);
}

// async global->LDS, 16B per lane; lds dest = wave-uniform base + lane*16
__device__ __forceinline__ void gl_lds16(const void* g, void* l) {
    __builtin_amdgcn_global_load_lds(
        (__attribute__((address_space(1))) void*)const_cast<void*>(g),
        (__attribute__((address_space(3))) void*)l, 16, 0, 0);
}

#define SWZ(r, byte) ((byte) ^ (((r) & 7) << 4))

// ---------------------------------------------------------------------------
// K1: prep. blocks 0..2047: per-row L2 norm -> hn (normalized bf16) + nrm
// (= sqrt(max(ss,eps)), the inverse of inv_norm). blocks 2048..2559:
// Wt[n][k] = bf16(W[k][n]).
// ---------------------------------------------------------------------------
__global__ __launch_bounds__(256) void k_prep(const float* __restrict__ h,
                                              const float* __restrict__ W,
                                              ushort* __restrict__ hn,
                                              ushort* __restrict__ Wt,
                                              float* __restrict__ nrm) {
    if (blockIdx.x < 2048) {
        int row = (blockIdx.x * 256 + threadIdx.x) >> 6;
        int lane = threadIdx.x & 63;
        float4 v = *reinterpret_cast<const float4*>(h + (size_t)row * F + lane * 4);
        float s = v.x * v.x + v.y * v.y + v.z * v.z + v.w * v.w;
        #pragma unroll
        for (int off = 32; off; off >>= 1) s += __shfl_xor(s, off, 64);
        float sn = fmaxf(s, 1e-12f);
        float inv = rsqrtf(sn);
        ushort4 on;
        on.x = f2bf(v.x * inv); on.y = f2bf(v.y * inv);
        on.z = f2bf(v.z * inv); on.w = f2bf(v.w * inv);
        *reinterpret_cast<ushort4*>(hn + (size_t)row * F + lane * 4) = on;
        if (lane == 0) nrm[row] = sn * inv;  // = sqrt(sn) = 1/inv_norm
    } else {
        int idx = (blockIdx.x - 2048) * 256 + threadIdx.x;  // coalesced over n
        int k = idx >> 9;
        int n = idx & 511;
        Wt[(size_t)n * F + k] = f2bf(W[idx]);
    }
}

// ---------------------------------------------------------------------------
// K2: fused MFMA kernel, XCD-chunked role mix. For XCD x = bid&7, q = bid>>3:
//   q <  64: proj block sid = x*64+q  -> tile 64(M)x128(N) of batch x rows
//   q >= 64: adj  pair  p  = x*36+(q-64), batch b = x, tiles ti<=tj (symmetry:
//            writes both (i-rows, j-words) and transposed (j-rows, i-words))
// Staging via global_load_lds w=16 with pre-swizzled per-lane source (m173).
// ---------------------------------------------------------------------------
__global__ __launch_bounds__(256) void k_gemm(const ushort* __restrict__ hn,
                                              const ushort* __restrict__ Wt,
                                              const float* __restrict__ nrm,
                                              const float* __restrict__ a,
                                              float* __restrict__ ht,
                                              float* __restrict__ out,
                                              float* __restrict__ src,
                                              float* __restrict__ tgt,
                                              unsigned* __restrict__ adj) {
    __shared__ __align__(16) ushort As[128 * 64];  // 16KB
    __shared__ __align__(16) ushort Bs[128 * 64];  // 16KB
    __shared__ float norms[64];
    const int x = blockIdx.x & 7;
    const int q = blockIdx.x >> 3;
    const int t = threadIdx.x;
    const int lane = t & 63;
    const int w = t >> 6;
    const int wr = w >> 1, wc = w & 1;
    const int lr = lane >> 3;                  // row within 8-row chunk
    const int lg = ((lane & 7) ^ lr) << 4;     // pre-swizzled source granule

    if (q < 64) {
        // ---------------- projection path ----------------
        const int sid = x * 64 + q;
        const int m0 = (sid >> 2) * 64;
        const int n0 = (sid & 3) * 128;
        if (t < 64) norms[t] = nrm[m0 + t];
        const char* aB = (const char*)hn + (size_t)(m0 + lr) * 512 + lg;
        const char* bB = (const char*)Wt + (size_t)(n0 + lr) * 512 + lg;
        f32x16 acc[2] = {};

        for (int f2 = 0; f2 < 512; f2 += 128) {   // byte offset of K-step
            __syncthreads();
            #pragma unroll
            for (int k = 0; k < 2; ++k) {          // A: 8 chunks / 4 waves
                int c = w * 2 + k;
                gl_lds16(aB + (size_t)c * 4096 + f2, (char*)As + c * 1024);
            }
            #pragma unroll
            for (int k = 0; k < 4; ++k) {          // B: 16 chunks / 4 waves
                int c = w * 4 + k;
                gl_lds16(bB + (size_t)c * 4096 + f2, (char*)Bs + c * 1024);
            }
            __syncthreads();
            #pragma unroll
            for (int kc = 0; kc < 4; ++kc) {
                int kb = kc * 32 + (lane >> 5) * 16;
                int ra = wr * 32 + (lane & 31);
                bf16x8 af = *reinterpret_cast<const bf16x8*>((char*)As + ra * 128 + SWZ(ra, kb));
                #pragma unroll
                for (int tc = 0; tc < 2; ++tc) {
                    int rb = wc * 64 + tc * 32 + (lane & 31);
                    bf16x8 bf = *reinterpret_cast<const bf16x8*>((char*)Bs + rb * 128 + SWZ(rb, kb));
                    acc[tc] = __builtin_amdgcn_mfma_f32_32x32x16_bf16(af, bf, acc[tc], 0, 0, 0);
                }
            }
        }
        // epilogue: scale by row norm, store to ht AND out (same flat layout)
        const int head = (n0 >> 6) + wc;
        #pragma unroll
        for (int tc = 0; tc < 2; ++tc) {
            int d = tc * 32 + (lane & 31);
            #pragma unroll
            for (int reg = 0; reg < 16; ++reg) {
                int ml = wr * 32 + (reg & 3) + 8 * (reg >> 2) + 4 * (lane >> 5);
                int m = m0 + ml;
                int b = m >> 10, n = m & 1023;
                float v = acc[tc][reg] * norms[ml];
                size_t idx = ((size_t)((b * H + head) * N + n)) * D + d;
                ht[idx] = v;
                out[idx] = v;
            }
        }
        // fused src/tgt (scaled by norm after reduce)
        const int dl = lane & 31;
        float as0 = a[head * 128 + dl];
        float as1 = a[head * 128 + 32 + dl];
        float at0 = a[head * 128 + 64 + dl];
        float at1 = a[head * 128 + 96 + dl];
        #pragma unroll
        for (int reg = 0; reg < 16; ++reg) {
            float s  = acc[0][reg] * as0 + acc[1][reg] * as1;
            float tg = acc[0][reg] * at0 + acc[1][reg] * at1;
            #pragma unroll
            for (int off = 16; off; off >>= 1) {
                s  += __shfl_xor(s, off, 64);
                tg += __shfl_xor(tg, off, 64);
            }
            if (dl == 0) {
                int ml = wr * 32 + (reg & 3) + 8 * (reg >> 2) + 4 * (lane >> 5);
                int m = m0 + ml;
                int b = m >> 10, n = m & 1023;
                float sc = norms[ml];
                size_t idx = (size_t)(b * H + head) * N + n;
                src[idx] = s * sc;
                tgt[idx] = tg * sc;
            }
        }
    } else {
        // ---------------- adjacency path (upper triangle) ----------------
        const int b = x;
        int pp = q - 64;           // 0..35 -> (ti<=tj)
        int ti = 0;
        while (pp >= 8 - ti) { pp -= 8 - ti; ++ti; }
        const int tj = ti + pp;
        const int i0 = ti * 128, j0 = tj * 128;
        const char* hbB = (const char*)hn + (size_t)b * N * 512;
        const char* aB = hbB + (size_t)(i0 + lr) * 512 + lg;
        const char* bB = hbB + (size_t)(j0 + lr) * 512 + lg;
        f32x16 acc[2][2] = {};

        for (int f2 = 0; f2 < 512; f2 += 128) {
            __syncthreads();
            #pragma unroll
            for (int k = 0; k < 4; ++k) {          // 16+16 chunks / 4 waves
                int c = w * 4 + k;
                gl_lds16(aB + (size_t)c * 4096 + f2, (char*)As + c * 1024);
                gl_lds16(bB + (size_t)c * 4096 + f2, (char*)Bs + c * 1024);
            }
            __syncthreads();
            #pragma unroll
            for (int kc = 0; kc < 4; ++kc) {
                int kb = kc * 32 + (lane >> 5) * 16;
                bf16x8 af[2], bfr[2];
                #pragma unroll
                for (int tr = 0; tr < 2; ++tr) {
                    int r = wr * 64 + tr * 32 + (lane & 31);
                    af[tr] = *reinterpret_cast<const bf16x8*>((char*)As + r * 128 + SWZ(r, kb));
                }
                #pragma unroll
                for (int tc = 0; tc < 2; ++tc) {
                    int r = wc * 64 + tc * 32 + (lane & 31);
                    bfr[tc] = *reinterpret_cast<const bf16x8*>((char*)Bs + r * 128 + SWZ(r, kb));
                }
                #pragma unroll
                for (int tr = 0; tr < 2; ++tr)
                    #pragma unroll
                    for (int tc = 0; tc < 2; ++tc)
                        acc[tr][tc] = __builtin_amdgcn_mfma_f32_32x32x16_bf16(af[tr], bfr[tc], acc[tr][tc], 0, 0, 0);
            }
        }
        #pragma unroll
        for (int tr = 0; tr < 2; ++tr) {
            #pragma unroll
            for (int tc = 0; tc < 2; ++tc) {
                int wordcol = (j0 + wc * 64 + tc * 32) >> 5;
                int rb0 = i0 + wr * 64 + tr * 32;
                unsigned tw = 0;
                #pragma unroll
                for (int reg = 0; reg < 16; ++reg) {
                    bool pr = acc[tr][tc][reg] > 0.5f;
                    unsigned long long msk = __ballot(pr);
                    int rbase = rb0 + (reg & 3) + 8 * (reg >> 2);
                    if (lane == 0)
                        adj[(size_t)(b * N + rbase) * 32 + wordcol] = (unsigned)msk;
                    if (lane == 32)
                        adj[(size_t)(b * N + rbase + 4) * 32 + wordcol] = (unsigned)(msk >> 32);
                    tw |= (pr ? 1u : 0u) << ((reg & 3) + 8 * (reg >> 2) + 4 * (lane >> 5));
                }
                if (ti != tj) {
                    // mirrored write: word for column cj over this 32-row group
                    tw |= (unsigned)__shfl_xor((int)tw, 32, 64);
                    if (lane < 32) {
                        int cj = j0 + wc * 64 + tc * 32 + lane;
                        adj[(size_t)(b * N + cj) * 32 + (rb0 >> 5)] = tw;
                    }
                }
            }
        }
    }
}

// ---------------------------------------------------------------------------
// K3: fixup-only attention. One wave per (b,i) row; if the adjacency row is a
// singleton (diagonal only), out already holds ht row -> nothing to do.
// Otherwise full online-softmax over neighbors for all 8 heads.
// ---------------------------------------------------------------------------
__global__ void k_attn(const float* __restrict__ ht, const float* __restrict__ src,
                       const float* __restrict__ tgt, const unsigned* __restrict__ adj,
                       float* __restrict__ out) {
    int row = (blockIdx.x * 256 + threadIdx.x) >> 6;  // b*N+i
    int lane = threadIdx.x & 63;
    if (row >= B * N) return;
    const unsigned* arow = adj + (size_t)row * 32;
    unsigned myword = (lane < 32) ? arow[lane] : 0u;
    int cnt = __popc(myword);
    #pragma unroll
    for (int off = 32; off; off >>= 1) cnt += __shfl_xor(cnt, off, 64);
    if (cnt <= 1) return;  // singleton: out row == ht row already written

    unsigned long long nz = __ballot(myword != 0u);
    int b = row >> 10, i = row & 1023;
    for (int hh = 0; hh < H; ++hh) {
        int bh = b * H + hh;
        const float* htb = ht + (size_t)bh * N * D;
        const float* tgtb = tgt + (size_t)bh * N;
        float s_i = src[(size_t)bh * N + i];
        float m = -INFINITY, l = 0.f, acc = 0.f;
        unsigned long long qz = nz;
        while (qz) {
            int wt = __builtin_ctzll(qz);
            qz &= qz - 1;
            unsigned word = (unsigned)__shfl((int)myword, wt, 64);
            while (word) {
                int jl = __builtin_ctz(word);
                word &= word - 1;
                int j = wt * 32 + jl;
                float e = s_i + tgtb[j];
                e = e > 0.f ? e : 0.2f * e;
                float mn = fmaxf(m, e);
                float scl = __expf(m - mn);  // exp(-inf)=0 on first hit
                float p   = __expf(e - mn);
                l = l * scl + p;
                acc = acc * scl + p * htb[(size_t)j * D + lane];
                m = mn;
            }
        }
        out[((size_t)bh * N + i) * D + lane] = acc / l;
    }
}

// ---------------------------------------------------------------------------
extern "C" void kernel_launch(void* const* d_in, const int* in_sizes, int n_in,
                              void* d_out, int out_size, void* d_ws, size_t ws_size,
                              hipStream_t stream) {
    const float* h = (const float*)d_in[0];   // [B,N,F]
    const float* W = (const float*)d_in[1];   // [F, H*D]
    const float* a = (const float*)d_in[2];   // [H, 2D, 1]
    float* out = (float*)d_out;               // [B,H,N,D] flat == [B,N,H*D] reshape

    char* ws = (char*)d_ws;
    unsigned* adj = (unsigned*)(ws + 0);          // 1 MB
    float*    src = (float*)(ws + 1048576);       // 256 KB
    float*    tgt = (float*)(ws + 1310720);       // 256 KB
    float*    ht  = (float*)(ws + 1572864);       // 16 MB
    ushort*   hn  = (ushort*)(ws + 18350080);     // 4 MB
    ushort*   Wt  = (ushort*)(ws + 22544384);     // 256 KB
    float*    nrm = (float*)(ws + 22806528);      // 32 KB

    k_prep<<<dim3(2560), 256, 0, stream>>>(h, W, hn, Wt, nrm);
    k_gemm<<<dim3(800), 256, 0, stream>>>(hn, Wt, nrm, a, ht, out, src, tgt, adj);
    k_attn<<<dim3((B * N) / 4), 256, 0, stream>>>(ht, src, tgt, adj, out);
}